// Round 2
// baseline (31.251 us; speedup 1.0000x reference)
//
#include <hip/hip_runtime.h>

// NeRF ray composition: rgb / accumulated_weights / depth / disparity.
// ONE WAVE PER RAY (4 rays per 256-thread block). No LDS, no barriers.
// 1024 points per ray processed in 4 chunks of 256 (4 points/lane/chunk);
// exclusive transmittance cumprod = per-chunk wave shfl_up scan + scalar
// carry across chunks; final wave shfl_down reduction, lane 0 writes.

#define NUM_RAYS 8192
#define P 1024
#define BLOCK 256
#define RAYS_PER_BLOCK 4

__global__ __launch_bounds__(256) void compose_rays_kernel(
    const float* __restrict__ rgb_in,     // [R, P, 3]
    const float* __restrict__ raw_alpha,  // [R, P]
    const float* __restrict__ z_vals,     // [R, P]
    const float* __restrict__ rays_dir,   // [R, 3]
    const int*   __restrict__ ppr,        // [1]
    float* __restrict__ out)              // rgb[3R] | acc[R] | depth[R] | disp[R]
{
    const int lane = threadIdx.x & 63;
    const int wid  = threadIdx.x >> 6;
    const int r    = blockIdx.x * RAYS_PER_BLOCK + wid;

    const float cf = (float)(*ppr) * (1.0f / 1024.0f);

    const float dx = rays_dir[r * 3 + 0];
    const float dy = rays_dir[r * 3 + 1];
    const float dz = rays_dir[r * 3 + 2];
    const float nrm = sqrtf(dx * dx + dy * dy + dz * dz);

    const size_t rowP = (size_t)r * P;

    // Preload all z (4 chunks x float4) — also feeds boundary shuffles.
    float4 z4[4];
#pragma unroll
    for (int it = 0; it < 4; ++it)
        z4[it] = *(const float4*)(z_vals + rowP + it * 256 + lane * 4);

    // z of the point AFTER this lane's 4 points, per chunk:
    //   lanes 0..62 -> next lane's z4[it].x ; lane 63 -> lane0's z4[it+1].x
    float znext[4];
#pragma unroll
    for (int it = 0; it < 4; ++it) {
        const float from_next_lane = __shfl_down(z4[it].x, 1);
        const float first_of_next  = (it < 3) ? __shfl(z4[it + 1].x, 0) : 0.0f;
        znext[it] = (lane == 63) ? first_of_next : from_next_lane;
    }
    const float zl = __shfl(z4[3].w, 63);   // z[P-1], broadcast

    float carry = 1.0f;                      // transmittance entering chunk
    float ws = 0.f, rs = 0.f, gs = 0.f, bs = 0.f, ds = 0.f;
    float wlast = 0.f;                       // weight of point P-1 (lane 63 only)

#pragma unroll
    for (int it = 0; it < 4; ++it) {
        const float4 a4 = *(const float4*)(raw_alpha + rowP + it * 256 + lane * 4);
        const float* rgbp = rgb_in + (size_t)r * (P * 3) + it * 768 + lane * 12;
        const float4 c0 = *(const float4*)(rgbp + 0);
        const float4 c1 = *(const float4*)(rgbp + 4);
        const float4 c2 = *(const float4*)(rgbp + 8);

        const float zv[4] = {z4[it].x, z4[it].y, z4[it].z, z4[it].w};
        const float av[4] = {a4.x, a4.y, a4.z, a4.w};
        float dists[4];
        dists[0] = (zv[1] - zv[0]) * nrm;
        dists[1] = (zv[2] - zv[1]) * nrm;
        dists[2] = (zv[3] - zv[2]) * nrm;
        dists[3] = ((it == 3 && lane == 63) ? 1e10f : (znext[it] - zv[3])) * nrm;

        float alpha[4], om[4];
        float local = 1.0f;
#pragma unroll
        for (int j = 0; j < 4; ++j) {
            const float ra = fmaxf(av[j], 0.0f);
            alpha[j] = 1.0f - expf(-ra * dists[j] * cf);
            om[j]    = 1.0f - alpha[j] + 1e-10f;
            local   *= om[j];
        }

        // wave-inclusive multiplicative scan of per-lane chunk products
        float v = local;
#pragma unroll
        for (int off = 1; off < 64; off <<= 1) {
            const float n = __shfl_up(v, off);
            if (lane >= off) v *= n;
        }
        const float total = __shfl(v, 63);
        float excl = __shfl_up(v, 1);
        if (lane == 0) excl = 1.0f;
        excl *= carry;
        carry *= total;

        const float rgbv[12] = {c0.x, c0.y, c0.z, c0.w, c1.x, c1.y, c1.z, c1.w,
                                c2.x, c2.y, c2.z, c2.w};
        float trun = excl;
#pragma unroll
        for (int j = 0; j < 4; ++j) {
            const float w = alpha[j] * trun;
            ws += w;
            rs += w * rgbv[3 * j + 0];
            gs += w * rgbv[3 * j + 1];
            bs += w * rgbv[3 * j + 2];
            if (it == 3 && lane == 63 && j == 3)
                wlast = w;                    // excluded from ds per reference
            else
                ds += w * zv[j];
            trun *= om[j];
        }
    }

    const float wl = __shfl(wlast, 63);       // broadcast last weight

    // wave reduction (lane 0 ends with the totals)
#pragma unroll
    for (int off = 32; off > 0; off >>= 1) {
        ws += __shfl_down(ws, off);
        rs += __shfl_down(rs, off);
        gs += __shfl_down(gs, off);
        bs += __shfl_down(bs, off);
        ds += __shfl_down(ds, off);
    }

    if (lane == 0) {
        const float depth = ds + (1.0f - ws + wl) * zl;
        const float disp  = 1.0f / fmaxf(1e-4f, depth / ws);
        out[r * 3 + 0] = rs;
        out[r * 3 + 1] = gs;
        out[r * 3 + 2] = bs;
        out[3 * NUM_RAYS + r] = ws;
        out[4 * NUM_RAYS + r] = depth;
        out[5 * NUM_RAYS + r] = disp;
    }
}

extern "C" void kernel_launch(void* const* d_in, const int* in_sizes, int n_in,
                              void* d_out, int out_size, void* d_ws, size_t ws_size,
                              hipStream_t stream) {
    const float* rgb_in    = (const float*)d_in[0];  // [8192,1024,3]
    const float* raw_alpha = (const float*)d_in[1];  // [8192,1024]
    const float* z_vals    = (const float*)d_in[2];  // [8192,1024]
    const float* rays_dir  = (const float*)d_in[3];  // [8192,3]
    // d_in[4] = pruning_mask (unused by the reference math)
    const int*   ppr       = (const int*)d_in[5];    // [1]
    float* out = (float*)d_out;

    compose_rays_kernel<<<NUM_RAYS / RAYS_PER_BLOCK, BLOCK, 0, stream>>>(
        rgb_in, raw_alpha, z_vals, rays_dir, ppr, out);
}

// Round 3
// 31.129 us; speedup vs baseline: 1.0039x; 1.0039x over previous
//
#include <hip/hip_runtime.h>

// NeRF ray composition: rgb / accumulated_weights / depth / disparity.
// One wave per ray (4 rays per 256-thread block), no LDS, no barriers.
// ALL 20 float4 loads per lane are issued up front (sched_barrier keeps
// them ahead of the shuffle-scan chains) so each wave has 20 VMEM ops in
// flight; __launch_bounds__(256,4) caps VGPR at 128 for 4 waves/SIMD.

#define NUM_RAYS 8192
#define P 1024
#define BLOCK 256
#define RAYS_PER_BLOCK 4

__global__ __launch_bounds__(256, 4) void compose_rays_kernel(
    const float* __restrict__ rgb_in,     // [R, P, 3]
    const float* __restrict__ raw_alpha,  // [R, P]
    const float* __restrict__ z_vals,     // [R, P]
    const float* __restrict__ rays_dir,   // [R, 3]
    const int*   __restrict__ ppr,        // [1]
    float* __restrict__ out)              // rgb[3R] | acc[R] | depth[R] | disp[R]
{
    const int lane = threadIdx.x & 63;
    const int wid  = threadIdx.x >> 6;
    const int r    = blockIdx.x * RAYS_PER_BLOCK + wid;

    const size_t rowP = (size_t)r * P;

    // ---- issue every load up front: 4 z + 4 alpha + 12 rgb float4 ----
    float4 z4[4], a4[4], c[4][3];
#pragma unroll
    for (int it = 0; it < 4; ++it) {
        z4[it] = *(const float4*)(z_vals    + rowP + it * 256 + lane * 4);
        a4[it] = *(const float4*)(raw_alpha + rowP + it * 256 + lane * 4);
        const float* rgbp = rgb_in + (size_t)r * (P * 3) + it * 768 + lane * 12;
        c[it][0] = *(const float4*)(rgbp + 0);
        c[it][1] = *(const float4*)(rgbp + 4);
        c[it][2] = *(const float4*)(rgbp + 8);
    }
    const float dx = rays_dir[r * 3 + 0];
    const float dy = rays_dir[r * 3 + 1];
    const float dz = rays_dir[r * 3 + 2];
    const float cf = (float)(*ppr) * (1.0f / 1024.0f);
    __builtin_amdgcn_sched_barrier(0);   // keep loads issued before compute

    const float nrm = sqrtf(dx * dx + dy * dy + dz * dz);

    // z of the point AFTER this lane's 4 points, per chunk
    float znext[4];
#pragma unroll
    for (int it = 0; it < 4; ++it) {
        const float from_next_lane = __shfl_down(z4[it].x, 1);
        const float first_of_next  = (it < 3) ? __shfl(z4[it + 1].x, 0) : 0.0f;
        znext[it] = (lane == 63) ? first_of_next : from_next_lane;
    }
    const float zl = __shfl(z4[3].w, 63);   // z[P-1]

    float carry = 1.0f;
    float ws = 0.f, rs = 0.f, gs = 0.f, bs = 0.f, ds = 0.f;
    float wlast = 0.f;

#pragma unroll
    for (int it = 0; it < 4; ++it) {
        const float zv[4] = {z4[it].x, z4[it].y, z4[it].z, z4[it].w};
        const float av[4] = {a4[it].x, a4[it].y, a4[it].z, a4[it].w};
        float dists[4];
        dists[0] = (zv[1] - zv[0]) * nrm;
        dists[1] = (zv[2] - zv[1]) * nrm;
        dists[2] = (zv[3] - zv[2]) * nrm;
        dists[3] = ((it == 3 && lane == 63) ? 1e10f : (znext[it] - zv[3])) * nrm;

        float alpha[4], om[4];
        float local = 1.0f;
#pragma unroll
        for (int j = 0; j < 4; ++j) {
            const float ra = fmaxf(av[j], 0.0f);
            alpha[j] = 1.0f - expf(-ra * dists[j] * cf);
            om[j]    = 1.0f - alpha[j] + 1e-10f;
            local   *= om[j];
        }

        // wave-inclusive multiplicative scan of per-lane chunk products
        float v = local;
#pragma unroll
        for (int off = 1; off < 64; off <<= 1) {
            const float n = __shfl_up(v, off);
            if (lane >= off) v *= n;
        }
        const float total = __shfl(v, 63);
        float excl = __shfl_up(v, 1);
        if (lane == 0) excl = 1.0f;
        excl *= carry;
        carry *= total;

        const float rgbv[12] = {
            c[it][0].x, c[it][0].y, c[it][0].z, c[it][0].w,
            c[it][1].x, c[it][1].y, c[it][1].z, c[it][1].w,
            c[it][2].x, c[it][2].y, c[it][2].z, c[it][2].w};
        float trun = excl;
#pragma unroll
        for (int j = 0; j < 4; ++j) {
            const float w = alpha[j] * trun;
            ws += w;
            rs += w * rgbv[3 * j + 0];
            gs += w * rgbv[3 * j + 1];
            bs += w * rgbv[3 * j + 2];
            if (it == 3 && lane == 63 && j == 3)
                wlast = w;                    // excluded from ds per reference
            else
                ds += w * zv[j];
            trun *= om[j];
        }
    }

    const float wl = __shfl(wlast, 63);

#pragma unroll
    for (int off = 32; off > 0; off >>= 1) {
        ws += __shfl_down(ws, off);
        rs += __shfl_down(rs, off);
        gs += __shfl_down(gs, off);
        bs += __shfl_down(bs, off);
        ds += __shfl_down(ds, off);
    }

    if (lane == 0) {
        const float depth = ds + (1.0f - ws + wl) * zl;
        const float disp  = 1.0f / fmaxf(1e-4f, depth / ws);
        out[r * 3 + 0] = rs;
        out[r * 3 + 1] = gs;
        out[r * 3 + 2] = bs;
        out[3 * NUM_RAYS + r] = ws;
        out[4 * NUM_RAYS + r] = depth;
        out[5 * NUM_RAYS + r] = disp;
    }
}

extern "C" void kernel_launch(void* const* d_in, const int* in_sizes, int n_in,
                              void* d_out, int out_size, void* d_ws, size_t ws_size,
                              hipStream_t stream) {
    const float* rgb_in    = (const float*)d_in[0];  // [8192,1024,3]
    const float* raw_alpha = (const float*)d_in[1];  // [8192,1024]
    const float* z_vals    = (const float*)d_in[2];  // [8192,1024]
    const float* rays_dir  = (const float*)d_in[3];  // [8192,3]
    // d_in[4] = pruning_mask (unused by the reference math)
    const int*   ppr       = (const int*)d_in[5];    // [1]
    float* out = (float*)d_out;

    compose_rays_kernel<<<NUM_RAYS / RAYS_PER_BLOCK, BLOCK, 0, stream>>>(
        rgb_in, raw_alpha, z_vals, rays_dir, ppr, out);
}

// Round 4
// 30.736 us; speedup vs baseline: 1.0167x; 1.0128x over previous
//
#include <hip/hip_runtime.h>

// NeRF ray composition: rgb / accumulated_weights / depth / disparity.
// One wave per ray, 2 rays per 128-thread block. 1024 points per ray in
// 4 chunks of 256. The exclusive transmittance cumprod is a wave shfl_up
// scan with a scalar carry. NEW: rgb is loaded COALESCED (lane -> float4
// lane, lane+64, lane+128 of each chunk's 768-float block) and the
// per-point WEIGHTS are redistributed through a per-wave LDS array, so
// every VMEM instruction touches 16 contiguous cache lines (was 48 for
// the strided per-point rgb loads).

#define NUM_RAYS 8192
#define P 1024
#define BLOCK 128
#define RAYS_PER_BLOCK 2

__global__ __launch_bounds__(128) void compose_rays_kernel(
    const float* __restrict__ rgb_in,     // [R, P, 3]
    const float* __restrict__ raw_alpha,  // [R, P]
    const float* __restrict__ z_vals,     // [R, P]
    const float* __restrict__ rays_dir,   // [R, 3]
    const int*   __restrict__ ppr,        // [1]
    float* __restrict__ out)              // rgb[3R] | acc[R] | depth[R] | disp[R]
{
    const int lane = threadIdx.x & 63;
    const int wid  = threadIdx.x >> 6;
    const int r    = blockIdx.x * RAYS_PER_BLOCK + wid;

    // per-wave, per-chunk weight redistribution buffer
    __shared__ float w_lds[RAYS_PER_BLOCK][4][256];

    const float cf = (float)(*ppr) * (1.0f / 1024.0f);

    const float dx = rays_dir[r * 3 + 0];
    const float dy = rays_dir[r * 3 + 1];
    const float dz = rays_dir[r * 3 + 2];
    const float nrm = sqrtf(dx * dx + dy * dy + dz * dz);

    const size_t rowP = (size_t)r * P;

    // Preload all z (feeds chunk-boundary shuffles too).
    float4 z4[4];
#pragma unroll
    for (int it = 0; it < 4; ++it)
        z4[it] = *(const float4*)(z_vals + rowP + it * 256 + lane * 4);

    float znext[4];
#pragma unroll
    for (int it = 0; it < 4; ++it) {
        const float from_next_lane = __shfl_down(z4[it].x, 1);
        const float first_of_next  = (it < 3) ? __shfl(z4[it + 1].x, 0) : 0.0f;
        znext[it] = (lane == 63) ? first_of_next : from_next_lane;
    }
    const float zl = __shfl(z4[3].w, 63);   // z[P-1]

    float carry = 1.0f;
    float ws = 0.f, rs = 0.f, gs = 0.f, bs = 0.f, ds = 0.f;
    float wlast = 0.f;

#pragma unroll
    for (int it = 0; it < 4; ++it) {
        const float4 a4 = *(const float4*)(raw_alpha + rowP + it * 256 + lane * 4);
        // coalesced rgb: 3 x float4, lane-contiguous
        const float* cbase = rgb_in + (size_t)r * (P * 3) + it * 768;
        const float4 c0 = *(const float4*)(cbase + 4 * (lane));
        const float4 c1 = *(const float4*)(cbase + 4 * (lane + 64));
        const float4 c2 = *(const float4*)(cbase + 4 * (lane + 128));

        const float zv[4] = {z4[it].x, z4[it].y, z4[it].z, z4[it].w};
        const float av[4] = {a4.x, a4.y, a4.z, a4.w};
        float dists[4];
        dists[0] = (zv[1] - zv[0]) * nrm;
        dists[1] = (zv[2] - zv[1]) * nrm;
        dists[2] = (zv[3] - zv[2]) * nrm;
        dists[3] = ((it == 3 && lane == 63) ? 1e10f : (znext[it] - zv[3])) * nrm;

        float alpha[4], om[4];
        float local = 1.0f;
#pragma unroll
        for (int j = 0; j < 4; ++j) {
            const float ra = fmaxf(av[j], 0.0f);
            alpha[j] = 1.0f - expf(-ra * dists[j] * cf);
            om[j]    = 1.0f - alpha[j] + 1e-10f;
            local   *= om[j];
        }

        // wave-inclusive multiplicative scan of per-lane chunk products
        float v = local;
#pragma unroll
        for (int off = 1; off < 64; off <<= 1) {
            const float n = __shfl_up(v, off);
            if (lane >= off) v *= n;
        }
        const float total = __shfl(v, 63);
        float excl = __shfl_up(v, 1);
        if (lane == 0) excl = 1.0f;
        excl *= carry;
        carry *= total;

        // per-point weights + acc/depth sums (per-lane ownership)
        float4 wq;
        {
            float trun = excl;
            float w0 = alpha[0] * trun; trun *= om[0];
            float w1 = alpha[1] * trun; trun *= om[1];
            float w2 = alpha[2] * trun; trun *= om[2];
            float w3 = alpha[3] * trun;
            wq = make_float4(w0, w1, w2, w3);
            ws += w0 + w1 + w2 + w3;
            ds += w0 * zv[0] + w1 * zv[1] + w2 * zv[2];
            if (it == 3 && lane == 63)
                wlast = w3;                 // point P-1: excluded from ds
            else
                ds += w3 * zv[3];
        }

        // publish weights for this chunk, then gather for coalesced rgb
        *(float4*)(&w_lds[wid][it][lane * 4]) = wq;
        asm volatile("s_waitcnt lgkmcnt(0)" ::: "memory");

#pragma unroll
        for (int k = 0; k < 3; ++k) {
            const int   q  = lane + 64 * k;     // float4 index in [0,192)
            const int   f  = 4 * q;             // flat float index in [0,768)
            const int   p0 = f / 3;             // first point covered
            const int   m3 = f - 3 * p0;        // f % 3
            const float wA = w_lds[wid][it][p0];
            const float wB = w_lds[wid][it][p0 + 1];
            const float4 cv = (k == 0) ? c0 : (k == 1) ? c1 : c2;
            if (m3 == 0) {        // flats: ch 0,1,2,0  pts: p0,p0,p0,p0+1
                rs += cv.x * wA; gs += cv.y * wA; bs += cv.z * wA;
                rs += cv.w * wB;
            } else if (m3 == 1) { // ch 1,2,0,1  pts: p0,p0,p0+1,p0+1
                gs += cv.x * wA; bs += cv.y * wA;
                rs += cv.z * wB; gs += cv.w * wB;
            } else {              // ch 2,0,1,2  pts: p0,p0+1,p0+1,p0+1
                bs += cv.x * wA;
                rs += cv.y * wB; gs += cv.z * wB; bs += cv.w * wB;
            }
        }
    }

    const float wl = __shfl(wlast, 63);

#pragma unroll
    for (int off = 32; off > 0; off >>= 1) {
        ws += __shfl_down(ws, off);
        rs += __shfl_down(rs, off);
        gs += __shfl_down(gs, off);
        bs += __shfl_down(bs, off);
        ds += __shfl_down(ds, off);
    }

    if (lane == 0) {
        const float depth = ds + (1.0f - ws + wl) * zl;
        const float disp  = 1.0f / fmaxf(1e-4f, depth / ws);
        out[r * 3 + 0] = rs;
        out[r * 3 + 1] = gs;
        out[r * 3 + 2] = bs;
        out[3 * NUM_RAYS + r] = ws;
        out[4 * NUM_RAYS + r] = depth;
        out[5 * NUM_RAYS + r] = disp;
    }
}

extern "C" void kernel_launch(void* const* d_in, const int* in_sizes, int n_in,
                              void* d_out, int out_size, void* d_ws, size_t ws_size,
                              hipStream_t stream) {
    const float* rgb_in    = (const float*)d_in[0];  // [8192,1024,3]
    const float* raw_alpha = (const float*)d_in[1];  // [8192,1024]
    const float* z_vals    = (const float*)d_in[2];  // [8192,1024]
    const float* rays_dir  = (const float*)d_in[3];  // [8192,3]
    // d_in[4] = pruning_mask (unused by the reference math)
    const int*   ppr       = (const int*)d_in[5];    // [1]
    float* out = (float*)d_out;

    compose_rays_kernel<<<NUM_RAYS / RAYS_PER_BLOCK, BLOCK, 0, stream>>>(
        rgb_in, raw_alpha, z_vals, rays_dir, ppr, out);
}